// Round 9
// baseline (389.638 us; speedup 1.0000x reference)
//
#include <hip/hip_runtime.h>

// Problem constants
#define DIM   180
#define HEADS 6
#define HD    30
#define NKEY  144
#define NGS   2304
#define BATCH 64
#define TQ    128               // R9: 128-query tile, 512 threads, 8 waves
#define QT    18                // q-tiles (2304/128)
#define WPAD  192               // padded model dim (6 k-tiles of 32)
#define SXS   200               // sXQ row stride u16 (400 B, rows 16B-aligned, 2-way banks)
#define KROW  32                // Kb row stride u16 (DENSE 64 B rows, XOR-swizzled cols)
#define VROW  152               // VbT row stride u16 (304 B -> 2-way-conflict sV reads)
#define KB_STRIDE (NKEY * KROW) // 4608 u16 per (b,h) = 9216 B dense
#define VB_STRIDE (32 * VROW)   // 4864 u16 per (b,h) = 9728 B dense

typedef unsigned short u16;
typedef short v8s __attribute__((ext_vector_type(8)));   // 8 x bf16 MFMA operand
typedef float v4f __attribute__((ext_vector_type(4)));   // 4 x f32 MFMA acc

__device__ __forceinline__ float bf2f(u16 u) {
    union { unsigned int i; float f; } w; w.i = ((unsigned int)u) << 16; return w.f;
}
__device__ __forceinline__ u16 f2bf(float f) {
    union { float f; unsigned int i; } w; w.f = f;
    unsigned int r = w.i + 0x7fffu + ((w.i >> 16) & 1u);
    return (u16)(r >> 16);
}
// single-instruction RNE f32->bf16 pair (R5)
__device__ __forceinline__ unsigned cvt_pk_bf16(float lo, float hi) {
    unsigned r;
    asm("v_cvt_pk_bf16_f32 %0, %1, %2" : "=v"(r) : "v"(lo), "v"(hi));
    return r;
}
__device__ __forceinline__ uint2 pack4(const v4f& x) {
    return make_uint2(cvt_pk_bf16(x[0], x[1]), cvt_pk_bf16(x[2], x[3]));
}
// async global->LDS copy, 16B per lane, linear LDS dest (R7, verified)
__device__ __forceinline__ void gload_lds16(const u16* g, u16* l) {
    __builtin_amdgcn_global_load_lds(
        (const __attribute__((address_space(1))) unsigned int*)g,
        (__attribute__((address_space(3))) unsigned int*)l, 16, 0, 0);
}

// ---------------------------------------------------------------------------
// R9: occupancy via BIGGER blocks. R0-R8 all sat at 12 waves/CU (3/SIMD),
// LDS-bound at 3 blocks/CU; every fix bought ~5%. Now: TQ=128, 512 threads,
// 8 waves; LDS = 51200(sXQ) + 18432(sK dbuf) + 9728(sV) = 79360 B -> 2
// blocks/CU = 16 waves/CU (4/SIMD, +33%). Grid 1152 (2.25 rounds vs 3);
// K/V staging per 128 queries (halved). Head-loop per-wave code identical
// to R8 (sigma + permlane32_swap in-register P, tree softmax, 2 bar/head).
// Q-proj/out-proj use a 2x4 row-group x col-group wave decomposition.
// ---------------------------------------------------------------------------

// Weight prep: WqT[j][k] = Wq[k][j]; WpT[j][k'] with k' = h*32+dd (32-padded
// head-slab k-layout matching where attn leaves x in LDS), k = h*30+dd.
__global__ __launch_bounds__(256) void wt_prep_kernel(
    const float* __restrict__ Wq, const float* __restrict__ Wp,
    u16* __restrict__ WqT, u16* __restrict__ WpT) {
    int idx = blockIdx.x * 256 + threadIdx.x;        // < 2*192*192
    int sel = idx >= WPAD * WPAD;
    int rr  = sel ? idx - WPAD * WPAD : idx;
    int j = rr / WPAD, k = rr - j * WPAD;
    float v;
    if (!sel) {
        v = (j < DIM && k < DIM) ? Wq[k * DIM + j] : 0.f;
        WqT[j * WPAD + k] = f2bf(v);
    } else {
        int h = k >> 5, dd = k & 31;
        v = (j < DIM && dd < HD) ? Wp[(h * HD + dd) * DIM + j] : 0.f;
        WpT[j * WPAD + k] = f2bf(v);
    }
}

// ---------------------------------------------------------------------------
// Bias pre-gather in S^T C-fragment order WITH key sigma (R1/R8): tile
// (h, g=q/16, t=n/16); lane (l15,quad) holds C-rows 16t+quad*4+r carrying
// keys 16t+pg*4+r, pg = sigma group (0,2,1,3). col q=16g+l15. Values
// pre-scaled by log2e (softmax runs in exp2 domain).
__global__ __launch_bounds__(256) void gather_bias_kernel(
    const float* __restrict__ table, const int* __restrict__ rpi,
    u16* __restrict__ biasCT) {
    const float LOG2E = 1.4426950408889634f;
    int i = blockIdx.x * 256 + threadIdx.x;          // < 7776*64 = 497664
    int lane = i & 63;
    int tile = i >> 6;
    int t = tile % 9;
    int rem = tile / 9;
    int g = rem % 144;
    int h = rem / 144;
    int qd = (lane >> 4) & 3;
    int pg = ((qd & 1) << 1) | (qd >> 1);            // sigma group: 0,2,1,3
    int q  = 16 * g + (lane & 15);
    int n0 = 16 * t + pg * 4;
    const int4 rr = *(const int4*)&rpi[q * NKEY + n0];
    unsigned lo = (unsigned)f2bf(table[rr.x * HEADS + h] * LOG2E) |
                  ((unsigned)f2bf(table[rr.y * HEADS + h] * LOG2E) << 16);
    unsigned hi = (unsigned)f2bf(table[rr.z * HEADS + h] * LOG2E) |
                  ((unsigned)f2bf(table[rr.w * HEADS + h] * LOG2E) << 16);
    ((uint2*)biasCT)[i] = make_uint2(lo, hi);
}

// ---------------------------------------------------------------------------
// K/V projection -> bf16 fragment-ready global layouts (DENSE slabs):
//   Kb [b][h][n'][32]  n' = sigma(n), cols XOR-swizzled by (n'&3)
//                      (d pads = 0 via memset)        -- 9216 B per (b,h)
//   VbT[b][h][d][152]  natural key order (d rows 30,31 & col pads = 0)
__global__ __launch_bounds__(256) void kv_proj_kernel(
    const float* __restrict__ feat,
    const float* __restrict__ Wk, const float* __restrict__ bk,
    const float* __restrict__ Wv, const float* __restrict__ bv,
    u16* __restrict__ Kb, u16* __restrict__ VbT) {
    __shared__ float sF[16 * DIM];
    int b  = blockIdx.x / 9;
    int n0 = (blockIdx.x % 9) * 16;
    int tid = threadIdx.x;
    {
        const float4* src = (const float4*)(feat + (size_t)(b * NKEY + n0) * DIM);
        float4* dst = (float4*)sF;
        for (int i = tid; i < 16 * 45; i += 256) dst[i] = src[i];
    }
    __syncthreads();
    int j = tid;
    if (j < DIM) {
        float ak[16], av[16];
#pragma unroll
        for (int r = 0; r < 16; ++r) { ak[r] = 0.f; av[r] = 0.f; }
        const float4* sF4 = (const float4*)sF;
        for (int kc = 0; kc < 45; ++kc) {
            int kk = kc * 4;
            float wk0 = Wk[(kk + 0) * DIM + j], wk1 = Wk[(kk + 1) * DIM + j];
            float wk2 = Wk[(kk + 2) * DIM + j], wk3 = Wk[(kk + 3) * DIM + j];
            float wv0 = Wv[(kk + 0) * DIM + j], wv1 = Wv[(kk + 1) * DIM + j];
            float wv2 = Wv[(kk + 2) * DIM + j], wv3 = Wv[(kk + 3) * DIM + j];
#pragma unroll
            for (int r = 0; r < 16; ++r) {
                float4 g = sF4[r * 45 + kc];
                ak[r] = fmaf(g.x, wk0, ak[r]); ak[r] = fmaf(g.y, wk1, ak[r]);
                ak[r] = fmaf(g.z, wk2, ak[r]); ak[r] = fmaf(g.w, wk3, ak[r]);
                av[r] = fmaf(g.x, wv0, av[r]); av[r] = fmaf(g.y, wv1, av[r]);
                av[r] = fmaf(g.z, wv2, av[r]); av[r] = fmaf(g.w, wv3, av[r]);
            }
        }
        int h = j / HD, d = j - HD * h;
        u16* kp = Kb  + (size_t)(b * HEADS + h) * KB_STRIDE;
        u16* vp = VbT + (size_t)(b * HEADS + h) * VB_STRIDE;
        float bkj = bk[j], bvj = bv[j];
#pragma unroll
        for (int r = 0; r < 16; ++r) {
            // key n0+r -> row position n0+sigma(r) (sigma is an involution)
            int sr = ((r >> 2) == 1) ? r + 4 : ((r >> 2) == 2) ? r - 4 : r;
            int nn = n0 + sr;
            // XOR bank-swizzle: d-group (d>>3) stored at group (d>>3)^(nn&3)
            kp[nn * KROW + ((((d >> 3) ^ (nn & 3)) & 3) << 3) + (d & 7)] =
                f2bf(ak[r] + bkj);
            vp[d * VROW + n0 + r] = f2bf(av[r] + bvj);
        }
    }
}

// ---------------------------------------------------------------------------
// Fused MFMA attention. One block = (batch, 128-query tile), 8 waves.
// LDS: sXQ 51200 + sK dbuf 18432 + sV 9728 = 79360 B -> 2 blocks/CU,
// 16 waves/CU (4/SIMD). Head schedule identical to R8 (2 barriers/head,
// stages off-path). Wave w owns q rows 16w..16w+15 in the head loop;
// Q-proj/out-proj use wave = (wr = w>>2, wc = w&3): rows 64wr+16m+*,
// cols (3wc+jj)*16+l15.
__global__ __launch_bounds__(512, 4) void attn_kernel(
    const float* __restrict__ gs,
    const u16* __restrict__ WqT, const float* __restrict__ bq,
    const u16* __restrict__ WpT, const float* __restrict__ bp,
    const u16* __restrict__ Kb, const u16* __restrict__ VbT,
    const u16* __restrict__ biasCT, float* __restrict__ out) {

    __shared__ u16 sXQ[TQ * SXS];        // gs -> Q (head-slab) -> x  51200 B
    __shared__ u16 sK2[2 * NKEY * KROW]; // K double buffer          18432 B
    __shared__ u16 sV[32 * VROW];        // V(h) [d][n]               9728 B

    const int tid  = threadIdx.x;
    const int w    = tid >> 6;        // wave 0..7
    const int lane = tid & 63;
    const int l15  = tid & 15;
    const int quad = (tid >> 4) & 3;
    const int wr   = w >> 2;          // proj row-group 0..1
    const int wc   = w & 3;           // proj col-group 0..3
    // XCD swizzle: 1152 blocks = 8 xcd x (18 qt x 8 b). Each XCD owns 8
    // batches for all qt; concurrent window ~8qt x 8b -> ~2.7MB <= 4MB L2.
    const int bid  = blockIdx.x;
    const int i144 = bid >> 3;           // 0..143 within XCD
    const int qt   = i144 >> 3;          // 0..17
    const int b    = (bid & 7) * 8 + (i144 & 7);
    const int q0   = qt * TQ;
    // 1/sqrt(30) * log2e : softmax runs in the exp2 domain
    const float SCALE = 0.18257418583505536f * 1.4426950408889634f;

    // ---- stage gs tile -> sXQ (bf16, zero pad cols 180..195) ----
    {
        const float4* src = (const float4*)(gs + (size_t)(b * NGS + q0) * DIM);
        for (int i = tid; i < TQ * 45; i += 512) {
            int row = i / 45, c = i - row * 45;
            float4 g = src[row * 45 + c];
            *(uint2*)&sXQ[row * SXS + c * 4] =
                make_uint2(cvt_pk_bf16(g.x, g.y), cvt_pk_bf16(g.z, g.w));
        }
        for (int i = tid; i < TQ * 16; i += 512)
            sXQ[(i >> 4) * SXS + 180 + (i & 15)] = 0;
    }
    __syncthreads();

    // ---- Q-proj: q = (gs @ Wq + bq)*scale. Wave (wr,wc): 64-row group x
    //      48-col group, 72 MFMA/wave (same as R8). ----
    v4f qacc[12];
#pragma unroll
    for (int i = 0; i < 12; ++i) qacc[i] = (v4f){0.f, 0.f, 0.f, 0.f};
    for (int kt = 0; kt < 6; ++kt) {
        v8s A[4];
#pragma unroll
        for (int m = 0; m < 4; ++m)
            A[m] = *(const v8s*)&sXQ[(64 * wr + 16 * m + l15) * SXS +
                                     kt * 32 + quad * 8];
#pragma unroll
        for (int jj = 0; jj < 3; ++jj) {
            v8s B = *(const v8s*)&WqT[(size_t)((3 * wc + jj) * 16 + l15) * WPAD +
                                      kt * 32 + quad * 8];
#pragma unroll
            for (int m = 0; m < 4; ++m)
                qacc[jj * 4 + m] = __builtin_amdgcn_mfma_f32_16x16x32_bf16(
                    A[m], B, qacc[jj * 4 + m], 0, 0, 0);
        }
    }
    __syncthreads();   // all waves done READING gs before Q overwrites it
#pragma unroll
    for (int jj = 0; jj < 3; ++jj) {
        int j = (3 * wc + jj) * 16 + l15;
        if (j < DIM) {
            int h = j / HD;
            int pos = j + 2 * h;          // 32-padded head-slab column
            float bqj = bq[j];
#pragma unroll
            for (int m = 0; m < 4; ++m)
#pragma unroll
                for (int r = 0; r < 4; ++r) {
                    float v = (qacc[jj * 4 + m][r] + bqj) * SCALE;
                    sXQ[(64 * wr + 16 * m + quad * 4 + r) * SXS + pos] =
                        (u16)cvt_pk_bf16(v, v);
                }
        }
    }
    // zero Q pad cols d=30,31 of every head slab
    for (int i = tid; i < TQ * 12; i += 512) {
        int row = i / 12, c = i - row * 12;
        sXQ[row * SXS + (c >> 1) * 32 + 30 + (c & 1)] = 0;
    }

    // ---- prologue stages: K0, K1, V0 ----
    {
        const u16* kg0 = Kb + (size_t)(b * HEADS + 0) * KB_STRIDE;
        const u16* kg1 = Kb + (size_t)(b * HEADS + 1) * KB_STRIDE;
        const u16* vg0 = VbT + (size_t)(b * HEADS + 0) * VB_STRIDE;
        for (int i = tid; i < 576; i += 512) gload_lds16(kg0 + i * 8, sK2 + i * 8);
        for (int i = tid; i < 576; i += 512)
            gload_lds16(kg1 + i * 8, sK2 + NKEY * KROW + i * 8);
        for (int i = tid; i < 608; i += 512) gload_lds16(vg0 + i * 8, sV + i * 8);
    }
    __syncthreads();   // Q ready + K0/K1/V0 staged

    // ---- per-head attention (wave w owns q rows 16w+l15) ----
    for (int h = 0; h < HEADS; ++h) {
        const u16* sKc = sK2 + (h & 1) * (NKEY * KROW);

        // bias loads (per-wave, plain; consumed ~QK start). g = qt*8 + w.
        const u16* bgt = biasCT +
            ((size_t)((h * 144 + (qt * 8 + w)) * 9) * 256) + lane * 4;
        uint2 bb[9];
#pragma unroll
        for (int t = 0; t < 9; ++t) bb[t] = *(const uint2*)(bgt + t * 256);

        // Q B-fragment: own q rows (16w+l15), this head's 32-col slab
        v8s qa = *(const v8s*)&sXQ[(16 * w + l15) * SXS + h * 32 + quad * 8];

        // S^T = K · Q^T + bias^T ; C tile t: rowpos n'=16t+quad*4+r (key
        // sigma(n')), col q=16w+l15. sK read un-swizzles: group quad^(l15&3).
        v4f la[9];
#pragma unroll
        for (int t = 0; t < 9; ++t) {
            la[t][0] = bf2f((u16)(bb[t].x & 0xffff));
            la[t][1] = bf2f((u16)(bb[t].x >> 16));
            la[t][2] = bf2f((u16)(bb[t].y & 0xffff));
            la[t][3] = bf2f((u16)(bb[t].y >> 16));
        }
#pragma unroll
        for (int t = 0; t < 9; ++t) {
            v8s kb = *(const v8s*)&sKc[(16 * t + l15) * KROW +
                                       ((quad ^ (l15 & 3)) << 3)];
            la[t] = __builtin_amdgcn_mfma_f32_16x16x32_bf16(kb, qa, la[t], 0, 0, 0);
        }

        // softmax (exp2 domain), tree reductions
        float mt[9];
#pragma unroll
        for (int t = 0; t < 9; ++t)
            mt[t] = fmaxf(fmaxf(la[t][0], la[t][1]), fmaxf(la[t][2], la[t][3]));
        float m = fmaxf(fmaxf(fmaxf(fmaxf(mt[0], mt[1]), fmaxf(mt[2], mt[3])),
                              fmaxf(fmaxf(mt[4], mt[5]), fmaxf(mt[6], mt[7]))),
                        mt[8]);
        m = fmaxf(m, __shfl_xor(m, 16));
        m = fmaxf(m, __shfl_xor(m, 32));
        float st[9];
#pragma unroll
        for (int t = 0; t < 9; ++t) {
#pragma unroll
            for (int r = 0; r < 4; ++r)
                la[t][r] = __builtin_amdgcn_exp2f(la[t][r] - m);
            st[t] = (la[t][0] + la[t][1]) + (la[t][2] + la[t][3]);
        }
        float s = (((st[0] + st[1]) + (st[2] + st[3])) +
                   ((st[4] + st[5]) + (st[6] + st[7]))) + st[8];
        s += __shfl_xor(s, 16);
        s += __shfl_xor(s, 32);
        float inv = 1.f / s;   // applied to x outputs, not to P

        // pack P (UNNORMALIZED) rows to bf16 dwords, kept in registers
        unsigned sd0[9], sd1[9];
#pragma unroll
        for (int t = 0; t < 9; ++t) {
            sd0[t] = cvt_pk_bf16(la[t][0], la[t][1]);
            sd1[t] = cvt_pk_bf16(la[t][2], la[t][3]);
        }

        __syncthreads();   // barA: V(h)/K(h+1) stages drained; QK(h) done

        // x^T = V^T · P^T : A = V^T rows from sV (lane=d), B = P^T built
        // IN-REGISTER via sigma + v_permlane32_swap_b32 (R8, verified).
        v4f x0 = (v4f){0.f, 0.f, 0.f, 0.f}, x1 = x0;
#pragma unroll
        for (int kt = 0; kt < 5; ++kt) {
            unsigned d0, d1, d2, d3;
            if (kt < 4) {
                d0 = sd0[2 * kt];     d1 = sd1[2 * kt];
                d2 = sd0[2 * kt + 1]; d3 = sd1[2 * kt + 1];
            } else {
                d0 = sd0[8]; d1 = sd1[8]; d2 = 0u; d3 = 0u;
            }
            asm("v_permlane32_swap_b32 %0, %1" : "+v"(d0), "+v"(d2));
            asm("v_permlane32_swap_b32 %0, %1" : "+v"(d1), "+v"(d3));
            union { unsigned u[4]; v8s v; } pu;
            pu.u[0] = d0; pu.u[1] = d1; pu.u[2] = d2; pu.u[3] = d3;
            int co = kt * 32 + quad * 8;
            co = (co < NKEY) ? co : 0;       // pa is zero there (kt=4,q>=2)
            v8s a0 = *(const v8s*)&sV[l15 * VROW + co];
            v8s a1 = *(const v8s*)&sV[(16 + l15) * VROW + co];
            x0 = __builtin_amdgcn_mfma_f32_16x16x32_bf16(a0, pu.v, x0, 0, 0, 0);
            x1 = __builtin_amdgcn_mfma_f32_16x16x32_bf16(a1, pu.v, x1, 0, 0, 0);
        }
        // x^T C tile -> dead Q slab h (own rows); normalize by inv (8 muls).
        v4f y0, y1;
#pragma unroll
        for (int r = 0; r < 4; ++r) { y0[r] = x0[r] * inv; y1[r] = x1[r] * inv; }
        *(uint2*)&sXQ[(16 * w + l15) * SXS + h * 32 + quad * 4]      = pack4(y0);
        *(uint2*)&sXQ[(16 * w + l15) * SXS + h * 32 + 16 + quad * 4] = pack4(y1);

        if (h < HEADS - 1) {
            __syncthreads();   // barB: all waves done PV(h) reading sV
            if (h + 2 < HEADS) {   // stage K(h+2) into the buffer QK(h) used
                const u16* kg = Kb + (size_t)(b * HEADS + h + 2) * KB_STRIDE;
                u16* dst = sK2 + (h & 1) * (NKEY * KROW);
                for (int i = tid; i < 576; i += 512)
                    gload_lds16(kg + i * 8, dst + i * 8);
            }
            {                      // stage V(h+1)
                const u16* vg = VbT + (size_t)(b * HEADS + h + 1) * VB_STRIDE;
                for (int i = tid; i < 608; i += 512)
                    gload_lds16(vg + i * 8, sV + i * 8);
            }
        }
    }
    __syncthreads();   // x rows are read cross-wave by out-proj

    // ---- out-proj: out = x @ Wp + bp. Wave (wr,wc) as in Q-proj. ----
    {
        v4f acc[12];
#pragma unroll
        for (int i = 0; i < 12; ++i) acc[i] = (v4f){0.f, 0.f, 0.f, 0.f};
        for (int kt = 0; kt < 6; ++kt) {
            v8s A[4];
#pragma unroll
            for (int m = 0; m < 4; ++m)
                A[m] = *(const v8s*)&sXQ[(64 * wr + 16 * m + l15) * SXS +
                                         kt * 32 + quad * 8];
#pragma unroll
            for (int jj = 0; jj < 3; ++jj) {
                v8s B = *(const v8s*)&WpT[(size_t)((3 * wc + jj) * 16 + l15) * WPAD +
                                          kt * 32 + quad * 8];
#pragma unroll
                for (int m = 0; m < 4; ++m)
                    acc[jj * 4 + m] = __builtin_amdgcn_mfma_f32_16x16x32_bf16(
                        A[m], B, acc[jj * 4 + m], 0, 0, 0);
            }
        }
#pragma unroll
        for (int jj = 0; jj < 3; ++jj) {
            int j = (3 * wc + jj) * 16 + l15;
            if (j < DIM) {
                float bpj = bp[j];
#pragma unroll
                for (int m = 0; m < 4; ++m)
#pragma unroll
                    for (int r = 0; r < 4; ++r)
                        out[(size_t)(b * NGS + q0 + 64 * wr + 16 * m +
                                     quad * 4 + r) * DIM + j] =
                            acc[jj * 4 + m][r] + bpj;
            }
        }
    }
}

// ---------------------------------------------------------------------------
extern "C" void kernel_launch(void* const* d_in, const int* in_sizes, int n_in,
                              void* d_out, int out_size, void* d_ws, size_t ws_size,
                              hipStream_t stream) {
    const float* gs    = (const float*)d_in[0];
    const float* feat  = (const float*)d_in[1];
    const float* Wq    = (const float*)d_in[2];
    const float* bq    = (const float*)d_in[3];
    const float* Wk    = (const float*)d_in[4];
    const float* bk    = (const float*)d_in[5];
    const float* Wv    = (const float*)d_in[6];
    const float* bv    = (const float*)d_in[7];
    const float* Wp    = (const float*)d_in[8];
    const float* bp    = (const float*)d_in[9];
    const float* table = (const float*)d_in[10];
    const int*   rpi   = (const int*)d_in[11];
    float* out = (float*)d_out;

    // ws layout (u16 units): WqT | WpT | Kb | VbT | biasCT
    u16* WqT    = (u16*)d_ws;
    u16* WpT    = WqT + WPAD * WPAD;
    u16* Kb     = WpT + WPAD * WPAD;
    u16* VbT    = Kb  + (size_t)BATCH * HEADS * KB_STRIDE;
    u16* biasCT = VbT + (size_t)BATCH * HEADS * VB_STRIDE;

    // zero K pads (swizzled d=30,31 slots) and V pads: MFMA reads them
    size_t zero_bytes = (size_t)BATCH * HEADS * (KB_STRIDE + VB_STRIDE) * sizeof(u16);
    hipMemsetAsync(Kb, 0, zero_bytes, stream);

    wt_prep_kernel<<<dim3(2 * WPAD * WPAD / 256), dim3(256), 0, stream>>>(Wq, Wp, WqT, WpT);
    gather_bias_kernel<<<dim3(HEADS * 144 * 9 * 64 / 256), dim3(256), 0, stream>>>(
        table, rpi, biasCT);
    kv_proj_kernel<<<dim3(BATCH * 9), dim3(256), 0, stream>>>(feat, Wk, bk, Wv, bv, Kb, VbT);
    attn_kernel<<<dim3(BATCH * QT), dim3(512), 0, stream>>>(
        gs, WqT, bq, WpT, bp, Kb, VbT, biasCT, out);
}

// Round 10
// 359.827 us; speedup vs baseline: 1.0828x; 1.0828x over previous
//
#include <hip/hip_runtime.h>

// Problem constants
#define DIM   180
#define HEADS 6
#define HD    30
#define NKEY  144
#define NGS   2304
#define BATCH 64
#define TQ    64
#define QT    36                // q-tiles (2304/64)
#define WPAD  192               // padded model dim (6 k-tiles of 32)
#define SXS   200               // sXQ row stride u16 (400 B, rows 16B-aligned, 2-way banks)
#define KROW  32                // Kb row stride u16 (DENSE 64 B rows, XOR-swizzled cols)
#define VROW  152               // VbT row stride u16 (304 B -> 2-way-conflict sV reads)
#define TBL   9025              // bias table rows
#define KB_STRIDE (NKEY * KROW) // 4608 u16 per (b,h) = 9216 B dense
#define VB_STRIDE (32 * VROW)   // 4864 u16 per (b,h) = 9728 B dense

typedef unsigned short u16;
typedef short v8s __attribute__((ext_vector_type(8)));   // 8 x bf16 MFMA operand
typedef float v4f __attribute__((ext_vector_type(4)));   // 4 x f32 MFMA acc

__device__ __forceinline__ float bf2f(u16 u) {
    union { unsigned int i; float f; } w; w.i = ((unsigned int)u) << 16; return w.f;
}
__device__ __forceinline__ u16 f2bf(float f) {
    union { float f; unsigned int i; } w; w.f = f;
    unsigned int r = w.i + 0x7fffu + ((w.i >> 16) & 1u);
    return (u16)(r >> 16);
}
// single-instruction RNE f32->bf16 pair (R5)
__device__ __forceinline__ unsigned cvt_pk_bf16(float lo, float hi) {
    unsigned r;
    asm("v_cvt_pk_bf16_f32 %0, %1, %2" : "=v"(r) : "v"(lo), "v"(hi));
    return r;
}
__device__ __forceinline__ uint2 pack4(const v4f& x) {
    return make_uint2(cvt_pk_bf16(x[0], x[1]), cvt_pk_bf16(x[2], x[3]));
}
// async global->LDS copy, 16B per lane, linear LDS dest (R7, verified)
__device__ __forceinline__ void gload_lds16(const u16* g, u16* l) {
    __builtin_amdgcn_global_load_lds(
        (const __attribute__((address_space(1))) unsigned int*)g,
        (__attribute__((address_space(3))) unsigned int*)l, 16, 0, 0);
}

// ---------------------------------------------------------------------------
// R10: attn = R8 (150.4us, verified) + s_setprio around MFMA clusters (T5).
// R9's TQ=128 regressed (170us: 8-wave barrier convoys + write-line
// pathology) -> reverted. Prep-side experiment: bench-minus-attn is a
// constant ~211us never measured; gather_bias redone 6x leaner (one thread
// serves all 6 heads via pre-built bf16 tableP[9025][8], 16B-row aligned
// dwordx4 gathers; rpi read once instead of 6x; grid 1944->324 blocks).
// ---------------------------------------------------------------------------

// Weight prep + tableP build. idx: [0,W2) WqT | [W2,2*W2) WpT | rest tableP.
// WqT[j][k]=Wq[k][j]; WpT[j][k'] k'=h*32+dd head-slab layout;
// tableP[row][c] = bf16(table[row][c] * log2e), rows padded to 8 (16 B).
__global__ __launch_bounds__(256) void wt_prep_kernel(
    const float* __restrict__ Wq, const float* __restrict__ Wp,
    const float* __restrict__ table,
    u16* __restrict__ WqT, u16* __restrict__ WpT, u16* __restrict__ tableP) {
    const float LOG2E = 1.4426950408889634f;
    const int W2 = WPAD * WPAD;
    int idx = blockIdx.x * 256 + threadIdx.x;
    if (idx < W2) {
        int j = idx / WPAD, k = idx - j * WPAD;
        WqT[idx] = f2bf((j < DIM && k < DIM) ? Wq[k * DIM + j] : 0.f);
    } else if (idx < 2 * W2) {
        int rr = idx - W2;
        int j = rr / WPAD, k = rr - j * WPAD;
        int h = k >> 5, dd = k & 31;
        WpT[rr] = f2bf((j < DIM && dd < HD) ? Wp[(h * HD + dd) * DIM + j] : 0.f);
    } else {
        int r2 = idx - 2 * W2;
        if (r2 < TBL * 8) {
            int row = r2 >> 3, c = r2 & 7;
            tableP[r2] = (c < 6) ? f2bf(table[row * 6 + c] * LOG2E) : (u16)0;
        }
    }
}

// ---------------------------------------------------------------------------
// Bias pre-gather, S^T C-fragment order WITH key sigma (R8). One thread per
// (g,t,lane) serves ALL 6 heads: 1 rpi int4 + 4 aligned dwordx4 tableP rows
// + 6 coalesced uint2 writes. Output layout identical to R8:
// biasCT[((h*144+g)*9+t)*64 + lane] = {keys pg*4..+3 packed}.
__global__ __launch_bounds__(256) void gather_bias_kernel(
    const u16* __restrict__ tableP, const int* __restrict__ rpi,
    u16* __restrict__ biasCT) {
    int i = blockIdx.x * 256 + threadIdx.x;          // < 1296*64 = 82944
    int lane = i & 63;
    int tile = i >> 6;                               // g*9 + t
    int t = tile % 9;
    int g = tile / 9;
    int qd = (lane >> 4) & 3;
    int pg = ((qd & 1) << 1) | (qd >> 1);            // sigma group: 0,2,1,3
    int q  = 16 * g + (lane & 15);
    int n0 = 16 * t + pg * 4;
    const int4 rr = *(const int4*)&rpi[q * NKEY + n0];
    uint4 a0 = *(const uint4*)&tableP[(size_t)rr.x * 8];
    uint4 a1 = *(const uint4*)&tableP[(size_t)rr.y * 8];
    uint4 a2 = *(const uint4*)&tableP[(size_t)rr.z * 8];
    uint4 a3 = *(const uint4*)&tableP[(size_t)rr.w * 8];
    const unsigned* p0 = (const unsigned*)&a0;
    const unsigned* p1 = (const unsigned*)&a1;
    const unsigned* p2 = (const unsigned*)&a2;
    const unsigned* p3 = (const unsigned*)&a3;
#pragma unroll
    for (int h = 0; h < 6; ++h) {
        int wd = h >> 1, sh = (h & 1) * 16;          // compile-time (unrolled)
        unsigned b0 = (p0[wd] >> sh) & 0xffffu;
        unsigned b1 = (p1[wd] >> sh) & 0xffffu;
        unsigned b2 = (p2[wd] >> sh) & 0xffffu;
        unsigned b3 = (p3[wd] >> sh) & 0xffffu;
        ((uint2*)biasCT)[(((size_t)h * 144 + g) * 9 + t) * 64 + lane] =
            make_uint2(b0 | (b1 << 16), b2 | (b3 << 16));
    }
}

// ---------------------------------------------------------------------------
// K/V projection -> bf16 fragment-ready global layouts (DENSE slabs):
//   Kb [b][h][n'][32]  n' = sigma(n), cols XOR-swizzled by (n'&3)
//                      (d pads = 0 via memset)        -- 9216 B per (b,h)
//   VbT[b][h][d][152]  natural key order (d rows 30,31 & col pads = 0)
__global__ __launch_bounds__(256) void kv_proj_kernel(
    const float* __restrict__ feat,
    const float* __restrict__ Wk, const float* __restrict__ bk,
    const float* __restrict__ Wv, const float* __restrict__ bv,
    u16* __restrict__ Kb, u16* __restrict__ VbT) {
    __shared__ float sF[16 * DIM];
    int b  = blockIdx.x / 9;
    int n0 = (blockIdx.x % 9) * 16;
    int tid = threadIdx.x;
    {
        const float4* src = (const float4*)(feat + (size_t)(b * NKEY + n0) * DIM);
        float4* dst = (float4*)sF;
        for (int i = tid; i < 16 * 45; i += 256) dst[i] = src[i];
    }
    __syncthreads();
    int j = tid;
    if (j < DIM) {
        float ak[16], av[16];
#pragma unroll
        for (int r = 0; r < 16; ++r) { ak[r] = 0.f; av[r] = 0.f; }
        const float4* sF4 = (const float4*)sF;
        for (int kc = 0; kc < 45; ++kc) {
            int kk = kc * 4;
            float wk0 = Wk[(kk + 0) * DIM + j], wk1 = Wk[(kk + 1) * DIM + j];
            float wk2 = Wk[(kk + 2) * DIM + j], wk3 = Wk[(kk + 3) * DIM + j];
            float wv0 = Wv[(kk + 0) * DIM + j], wv1 = Wv[(kk + 1) * DIM + j];
            float wv2 = Wv[(kk + 2) * DIM + j], wv3 = Wv[(kk + 3) * DIM + j];
#pragma unroll
            for (int r = 0; r < 16; ++r) {
                float4 g = sF4[r * 45 + kc];
                ak[r] = fmaf(g.x, wk0, ak[r]); ak[r] = fmaf(g.y, wk1, ak[r]);
                ak[r] = fmaf(g.z, wk2, ak[r]); ak[r] = fmaf(g.w, wk3, ak[r]);
                av[r] = fmaf(g.x, wv0, av[r]); av[r] = fmaf(g.y, wv1, av[r]);
                av[r] = fmaf(g.z, wv2, av[r]); av[r] = fmaf(g.w, wv3, av[r]);
            }
        }
        int h = j / HD, d = j - HD * h;
        u16* kp = Kb  + (size_t)(b * HEADS + h) * KB_STRIDE;
        u16* vp = VbT + (size_t)(b * HEADS + h) * VB_STRIDE;
        float bkj = bk[j], bvj = bv[j];
#pragma unroll
        for (int r = 0; r < 16; ++r) {
            // key n0+r -> row position n0+sigma(r) (sigma is an involution)
            int sr = ((r >> 2) == 1) ? r + 4 : ((r >> 2) == 2) ? r - 4 : r;
            int nn = n0 + sr;
            // XOR bank-swizzle: d-group (d>>3) stored at group (d>>3)^(nn&3)
            kp[nn * KROW + ((((d >> 3) ^ (nn & 3)) & 3) << 3) + (d & 7)] =
                f2bf(ak[r] + bkj);
            vp[d * VROW + n0 + r] = f2bf(av[r] + bvj);
        }
    }
}

// ---------------------------------------------------------------------------
// Fused MFMA attention (R8 structure, verified). One block = (batch, 64-q
// tile), 4 waves. LDS: sXQ 25600 + sK dbuf 18432 + sV 9728 = 53760 B -> 3
// blocks/CU. 2 barriers/head, stages off-path, sigma + permlane32_swap
// in-register P, tree softmax. R10: s_setprio(1) around MFMA clusters (T5).
__global__ __launch_bounds__(256, 3) void attn_kernel(
    const float* __restrict__ gs,
    const u16* __restrict__ WqT, const float* __restrict__ bq,
    const u16* __restrict__ WpT, const float* __restrict__ bp,
    const u16* __restrict__ Kb, const u16* __restrict__ VbT,
    const u16* __restrict__ biasCT, float* __restrict__ out) {

    __shared__ u16 sXQ[TQ * SXS];        // gs -> Q (head-slab) -> x  25600 B
    __shared__ u16 sK2[2 * NKEY * KROW]; // K double buffer          18432 B
    __shared__ u16 sV[32 * VROW];        // V(h) [d][n]               9728 B

    const int tid  = threadIdx.x;
    const int w    = tid >> 6;        // wave 0..3
    const int lane = tid & 63;
    const int l15  = tid & 15;
    const int quad = (tid >> 4) & 3;
    // R4 2D locality swizzle: each XCD owns 8 batches for all qt.
    const int bid  = blockIdx.x;
    const int i8   = bid >> 3;           // 0..287 within XCD
    const int qt   = i8 >> 3;            // 0..35
    const int b    = (bid & 7) * 8 + (i8 & 7);
    const int q0   = qt * TQ;
    // 1/sqrt(30) * log2e : softmax runs in the exp2 domain
    const float SCALE = 0.18257418583505536f * 1.4426950408889634f;

    // ---- stage gs tile -> sXQ (bf16, zero pad cols 180..195) ----
    {
        const float4* src = (const float4*)(gs + (size_t)(b * NGS + q0) * DIM);
        for (int i = tid; i < TQ * 45; i += 256) {
            int row = i / 45, c = i - row * 45;
            float4 g = src[row * 45 + c];
            *(uint2*)&sXQ[row * SXS + c * 4] =
                make_uint2(cvt_pk_bf16(g.x, g.y), cvt_pk_bf16(g.z, g.w));
        }
        for (int i = tid; i < TQ * 16; i += 256)
            sXQ[(i >> 4) * SXS + 180 + (i & 15)] = 0;
    }
    __syncthreads();

    // ---- Q-proj: q = (gs @ Wq + bq)*scale ----
    v4f qacc[12];
#pragma unroll
    for (int i = 0; i < 12; ++i) qacc[i] = (v4f){0.f, 0.f, 0.f, 0.f};
    __builtin_amdgcn_s_setprio(1);
    for (int kt = 0; kt < 6; ++kt) {
        v8s A[4];
#pragma unroll
        for (int m = 0; m < 4; ++m)
            A[m] = *(const v8s*)&sXQ[(16 * m + l15) * SXS + kt * 32 + quad * 8];
#pragma unroll
        for (int jj = 0; jj < 3; ++jj) {
            v8s B = *(const v8s*)&WqT[(size_t)((3 * w + jj) * 16 + l15) * WPAD +
                                      kt * 32 + quad * 8];
#pragma unroll
            for (int m = 0; m < 4; ++m)
                qacc[jj * 4 + m] = __builtin_amdgcn_mfma_f32_16x16x32_bf16(
                    A[m], B, qacc[jj * 4 + m], 0, 0, 0);
        }
    }
    __builtin_amdgcn_s_setprio(0);
    __syncthreads();   // all waves done READING gs before Q overwrites it
#pragma unroll
    for (int jj = 0; jj < 3; ++jj) {
        int j = (3 * w + jj) * 16 + l15;
        if (j < DIM) {
            int h = j / HD;
            int pos = j + 2 * h;          // 32-padded head-slab column
            float bqj = bq[j];
#pragma unroll
            for (int m = 0; m < 4; ++m)
#pragma unroll
                for (int r = 0; r < 4; ++r) {
                    float v = (qacc[jj * 4 + m][r] + bqj) * SCALE;
                    sXQ[(16 * m + quad * 4 + r) * SXS + pos] =
                        (u16)cvt_pk_bf16(v, v);
                }
        }
    }
    // zero Q pad cols d=30,31 of every head slab
    for (int i = tid; i < TQ * 12; i += 256) {
        int row = i / 12, c = i - row * 12;
        sXQ[row * SXS + (c >> 1) * 32 + 30 + (c & 1)] = 0;
    }

    // ---- prologue stages: K0, K1, V0 ----
    {
        const u16* kg0 = Kb + (size_t)(b * HEADS + 0) * KB_STRIDE;
        const u16* kg1 = Kb + (size_t)(b * HEADS + 1) * KB_STRIDE;
        const u16* vg0 = VbT + (size_t)(b * HEADS + 0) * VB_STRIDE;
        for (int i = tid; i < 576; i += 256) gload_lds16(kg0 + i * 8, sK2 + i * 8);
        for (int i = tid; i < 576; i += 256)
            gload_lds16(kg1 + i * 8, sK2 + NKEY * KROW + i * 8);
        for (int i = tid; i < 608; i += 256) gload_lds16(vg0 + i * 8, sV + i * 8);
    }
    __syncthreads();   // Q ready + K0/K1/V0 staged

    // ---- per-head attention ----
    for (int h = 0; h < HEADS; ++h) {
        const u16* sKc = sK2 + (h & 1) * (NKEY * KROW);

        // bias loads (per-wave, plain; consumed ~QK start)
        const u16* bgt = biasCT +
            ((size_t)((h * 144 + (qt * 4 + w)) * 9) * 256) + lane * 4;
        uint2 bb[9];
#pragma unroll
        for (int t = 0; t < 9; ++t) bb[t] = *(const uint2*)(bgt + t * 256);

        // Q B-fragment: own q rows (16w+l15), this head's 32-col slab
        v8s qa = *(const v8s*)&sXQ[(16 * w + l15) * SXS + h * 32 + quad * 8];

        // S^T = K · Q^T + bias^T ; C tile t: rowpos n'=16t+quad*4+r (key
        // sigma(n')), col q=16w+l15. sK read un-swizzles: group quad^(l15&3).
        v4f la[9];
#pragma unroll
        for (int t = 0; t < 9; ++t) {
            la[t][0] = bf2f((u16)(bb[t].x & 0xffff));
            la[t][1] = bf2f((u16)(bb[t].x >> 16));
            la[t][2] = bf2f((u16)(bb[t].y & 0xffff));
            la[t][3] = bf2f((u16)(bb[t].y >> 16));
        }
        __builtin_amdgcn_s_setprio(1);
#pragma unroll
        for (int t = 0; t < 9; ++t) {
            v8s kb = *(const v8s*)&sKc[(16 * t + l15) * KROW +
                                       ((quad ^ (l15 & 3)) << 3)];
            la[t] = __builtin_amdgcn_mfma_f32_16x16x32_bf16(kb, qa, la[t], 0, 0, 0);
        }
        __builtin_amdgcn_s_setprio(0);

        // softmax (exp2 domain), tree reductions
        float mt[9];
#pragma unroll
        for (int t = 0; t < 9; ++t)
            mt[t] = fmaxf(fmaxf(la[t][0], la[t][1]), fmaxf(la[t][2], la[t][3]));
        float m = fmaxf(fmaxf(fmaxf(fmaxf(mt[0], mt[1]), fmaxf(mt[2], mt[3])),
                              fmaxf(fmaxf(mt[4], mt[5]), fmaxf(mt[6], mt[7]))),
                        mt[8]);
        m = fmaxf(m, __shfl_xor(m, 16));
        m = fmaxf(m, __shfl_xor(m, 32));
        float st[9];
#pragma unroll
        for (int t = 0; t < 9; ++t) {
#pragma unroll
            for (int r = 0; r < 4; ++r)
                la[t][r] = __builtin_amdgcn_exp2f(la[t][r] - m);
            st[t] = (la[t][0] + la[t][1]) + (la[t][2] + la[t][3]);
        }
        float s = (((st[0] + st[1]) + (st[2] + st[3])) +
                   ((st[4] + st[5]) + (st[6] + st[7]))) + st[8];
        s += __shfl_xor(s, 16);
        s += __shfl_xor(s, 32);
        float inv = 1.f / s;   // applied to x outputs, not to P

        // pack P (UNNORMALIZED) rows to bf16 dwords, kept in registers
        unsigned sd0[9], sd1[9];
#pragma unroll
        for (int t = 0; t < 9; ++t) {
            sd0[t] = cvt_pk_bf16(la[t][0], la[t][1]);
            sd1[t] = cvt_pk_bf16(la[t][2], la[t][3]);
        }

        __syncthreads();   // barA: V(h)/K(h+1) stages drained; QK(h) done

        // x^T = V^T · P^T : A = V^T rows from sV (lane=d), B = P^T built
        // IN-REGISTER via sigma + v_permlane32_swap_b32 (R8, verified).
        v4f x0 = (v4f){0.f, 0.f, 0.f, 0.f}, x1 = x0;
        __builtin_amdgcn_s_setprio(1);
#pragma unroll
        for (int kt = 0; kt < 5; ++kt) {
            unsigned d0, d1, d2, d3;
            if (kt < 4) {
                d0 = sd0[2 * kt];     d1 = sd1[2 * kt];
                d2 = sd0[2 * kt + 1]; d3 = sd1[2 * kt + 1];
            } else {
                d0 = sd0[8]; d1 = sd1[8]; d2 = 0u; d3 = 0u;
            }
            asm("v_permlane32_swap_b32 %0, %1" : "+v"(d0), "+v"(d2));
            asm("v_permlane32_swap_b32 %0, %1" : "+v"(d1), "+v"(d3));
            union { unsigned u[4]; v8s v; } pu;
            pu.u[0] = d0; pu.u[1] = d1; pu.u[2] = d2; pu.u[3] = d3;
            int co = kt * 32 + quad * 8;
            co = (co < NKEY) ? co : 0;       // pa is zero there (kt=4,q>=2)
            v8s a0 = *(const v8s*)&sV[l15 * VROW + co];
            v8s a1 = *(const v8s*)&sV[(16 + l15) * VROW + co];
            x0 = __builtin_amdgcn_mfma_f32_16x16x32_bf16(a0, pu.v, x0, 0, 0, 0);
            x1 = __builtin_amdgcn_mfma_f32_16x16x32_bf16(a1, pu.v, x1, 0, 0, 0);
        }
        __builtin_amdgcn_s_setprio(0);
        // x^T C tile -> dead Q slab h; normalize by inv here (8 muls).
        v4f y0, y1;
#pragma unroll
        for (int r = 0; r < 4; ++r) { y0[r] = x0[r] * inv; y1[r] = x1[r] * inv; }
        *(uint2*)&sXQ[(16 * w + l15) * SXS + h * 32 + quad * 4]      = pack4(y0);
        *(uint2*)&sXQ[(16 * w + l15) * SXS + h * 32 + 16 + quad * 4] = pack4(y1);

        if (h < HEADS - 1) {
            __syncthreads();   // barB: all waves done PV(h) reading sV
            if (h + 2 < HEADS) {   // stage K(h+2) into the buffer QK(h) used
                const u16* kg = Kb + (size_t)(b * HEADS + h + 2) * KB_STRIDE;
                u16* dst = sK2 + (h & 1) * (NKEY * KROW);
                for (int i = tid; i < 576; i += 256)
                    gload_lds16(kg + i * 8, dst + i * 8);
            }
            {                      // stage V(h+1)
                const u16* vg = VbT + (size_t)(b * HEADS + h + 1) * VB_STRIDE;
                for (int i = tid; i < 608; i += 256)
                    gload_lds16(vg + i * 8, sV + i * 8);
            }
        }
    }
    __syncthreads();   // x rows are read cross-wave by out-proj

    // ---- out-proj: out = x @ Wp + bp ----
    {
        v4f acc[12];
#pragma unroll
        for (int i = 0; i < 12; ++i) acc[i] = (v4f){0.f, 0.f, 0.f, 0.f};
        __builtin_amdgcn_s_setprio(1);
        for (int kt = 0; kt < 6; ++kt) {
            v8s A[4];
#pragma unroll
            for (int m = 0; m < 4; ++m)
                A[m] = *(const v8s*)&sXQ[(16 * m + l15) * SXS + kt * 32 + quad * 8];
#pragma unroll
            for (int jj = 0; jj < 3; ++jj) {
                v8s B = *(const v8s*)&WpT[(size_t)((3 * w + jj) * 16 + l15) * WPAD +
                                          kt * 32 + quad * 8];
#pragma unroll
                for (int m = 0; m < 4; ++m)
                    acc[jj * 4 + m] = __builtin_amdgcn_mfma_f32_16x16x32_bf16(
                        A[m], B, acc[jj * 4 + m], 0, 0, 0);
            }
        }
        __builtin_amdgcn_s_setprio(0);
#pragma unroll
        for (int jj = 0; jj < 3; ++jj) {
            int j = (3 * w + jj) * 16 + l15;
            if (j < DIM) {
                float bpj = bp[j];
#pragma unroll
                for (int m = 0; m < 4; ++m)
#pragma unroll
                    for (int r = 0; r < 4; ++r)
                        out[(size_t)(b * NGS + q0 + 16 * m + quad * 4 + r) * DIM + j] =
                            acc[jj * 4 + m][r] + bpj;
            }
        }
    }
}

// ---------------------------------------------------------------------------
extern "C" void kernel_launch(void* const* d_in, const int* in_sizes, int n_in,
                              void* d_out, int out_size, void* d_ws, size_t ws_size,
                              hipStream_t stream) {
    const float* gs    = (const float*)d_in[0];
    const float* feat  = (const float*)d_in[1];
    const float* Wq    = (const float*)d_in[2];
    const float* bq    = (const float*)d_in[3];
    const float* Wk    = (const float*)d_in[4];
    const float* bk    = (const float*)d_in[5];
    const float* Wv    = (const float*)d_in[6];
    const float* bv    = (const float*)d_in[7];
    const float* Wp    = (const float*)d_in[8];
    const float* bp    = (const float*)d_in[9];
    const float* table = (const float*)d_in[10];
    const int*   rpi   = (const int*)d_in[11];
    float* out = (float*)d_out;

    // ws layout (u16 units): WqT | WpT | Kb | VbT | biasCT | tableP
    u16* WqT    = (u16*)d_ws;
    u16* WpT    = WqT + WPAD * WPAD;
    u16* Kb     = WpT + WPAD * WPAD;
    u16* VbT    = Kb  + (size_t)BATCH * HEADS * KB_STRIDE;
    u16* biasCT = VbT + (size_t)BATCH * HEADS * VB_STRIDE;
    u16* tableP = biasCT + (size_t)HEADS * 144 * 9 * 64 * 4;

    // zero K pads (swizzled d=30,31 slots) and V pads: MFMA reads them
    size_t zero_bytes = (size_t)BATCH * HEADS * (KB_STRIDE + VB_STRIDE) * sizeof(u16);
    hipMemsetAsync(Kb, 0, zero_bytes, stream);

    wt_prep_kernel<<<dim3((2 * WPAD * WPAD + TBL * 8 + 255) / 256), dim3(256), 0,
                     stream>>>(Wq, Wp, table, WqT, WpT, tableP);
    gather_bias_kernel<<<dim3(144 * 9 * 64 / 256), dim3(256), 0, stream>>>(
        tableP, rpi, biasCT);
    kv_proj_kernel<<<dim3(BATCH * 9), dim3(256), 0, stream>>>(feat, Wk, bk, Wv, bv, Kb, VbT);
    attn_kernel<<<dim3(BATCH * QT), dim3(256), 0, stream>>>(
        gs, WqT, bq, WpT, bp, Kb, VbT, biasCT, out);
}